// Round 3
// baseline (2848.089 us; speedup 1.0000x reference)
//
#include <hip/hip_runtime.h>
#include <math.h>

#define TT 8
#define NC 128
#define HH 128
#define WW 128
#define HWP (HH*WW)
#define IMG ((size_t)NC*HWP)

// ---------------- per-scale compile-time geometry ----------------
template<int S> struct SCg {
  static constexpr int PH   = 128 >> S;   // window height == width
  static constexpr int OH   = 1 << S;     // windows per side
  static constexpr int OHOW = OH*OH;
  static constexpr int N    = TT*OHOW;    // sequence length
  static constexpr int PHPW = PH*PH;
  static constexpr int D    = 32*PHPW;    // feature dim
  static constexpr int LPW  = 7 - S;      // log2(PW)
  static constexpr int LPP  = 14 - 2*S;   // log2(PH*PW)
};

// CS = channel stride of the tensor, CB0 = channel base offset.
// q/y live in the full 128-channel layout (CS=128, CB0=32*S);
// compact per-scale k/v live in a 32-channel layout (CS=32, CB0=0).
template<int S, int CS, int CB0>
__device__ __forceinline__ size_t win_addr(int b, int w, int f) {
  int t  = w >> (2*S);
  int rr = w & (SCg<S>::OHOW-1);
  int oy = rr >> S;
  int ox = rr & (SCg<S>::OH-1);
  int c  = f >> SCg<S>::LPP;
  int r2 = f & (SCg<S>::PHPW-1);
  int py = r2 >> SCg<S>::LPW;
  int px = r2 & (SCg<S>::PH-1);
  return ((size_t)((b*TT + t)*CS + CB0 + c))*HWP
       + (size_t)((oy*SCg<S>::PH + py)*WW) + ox*SCg<S>::PH + px;
}

// ---------------- 1a) Q projection (1x1 conv, all 128 channels) ----------
__global__ __launch_bounds__(256) void q_proj(
    const float* __restrict__ x,
    const float* __restrict__ wq, const float* __restrict__ bq,
    float* __restrict__ q)
{
  const int img = blockIdx.y;
  const int p0  = blockIdx.x * 128;
  __shared__ float wl[32][132];   // wl[cc][o]
  __shared__ float xl[32][132];   // xl[cc][p]
  const int tid = threadIdx.x;
  const int og = tid >> 4, pg = tid & 15;   // 16 o-groups x 16 p-groups, 8x8 each
  float acc[8][8];
  #pragma unroll
  for (int i=0;i<8;i++)
    #pragma unroll
    for (int j=0;j<8;j++) acc[i][j]=0.f;
  const float* xb = x + (size_t)img*IMG + p0;

  for (int k0=0; k0<128; k0+=32) {
    for (int idx=tid; idx<32*128; idx+=256) {      // w: lanes walk c (coalesced)
      int o = idx >> 5, cc = idx & 31;
      wl[cc][o] = wq[o*128 + k0 + cc];
    }
    for (int idx=tid; idx<32*128; idx+=256) {      // x: lanes walk p (coalesced)
      int cc = idx >> 7, p = idx & 127;
      xl[cc][p] = xb[(size_t)(k0+cc)*HWP + p];
    }
    __syncthreads();
    #pragma unroll
    for (int cc=0; cc<32; cc++) {
      float4 wf0 = *(const float4*)&wl[cc][og*8];
      float4 wf1 = *(const float4*)&wl[cc][og*8+4];
      float4 xf0 = *(const float4*)&xl[cc][pg*8];
      float4 xf1 = *(const float4*)&xl[cc][pg*8+4];
      float wv8[8] = {wf0.x,wf0.y,wf0.z,wf0.w,wf1.x,wf1.y,wf1.z,wf1.w};
      float xv8[8] = {xf0.x,xf0.y,xf0.z,xf0.w,xf1.x,xf1.y,xf1.z,xf1.w};
      #pragma unroll
      for (int i=0;i<8;i++)
        #pragma unroll
        for (int j=0;j<8;j++) acc[i][j] += wv8[i]*xv8[j];
    }
    __syncthreads();
  }
  #pragma unroll
  for (int i=0;i<8;i++) {
    int o = og*8 + i;
    float bs = bq[o];
    float* dst = q + ((size_t)img*NC + o)*HWP + p0 + pg*8;
    float4 r0 = {acc[i][0]+bs, acc[i][1]+bs, acc[i][2]+bs, acc[i][3]+bs};
    float4 r1 = {acc[i][4]+bs, acc[i][5]+bs, acc[i][6]+bs, acc[i][7]+bs};
    *(float4*)dst       = r0;
    *(float4*)(dst + 4) = r1;
  }
}

// ---------------- 1b) per-scale K,V slice projection (32+32 outputs) ------
// Writes compact (img, 32, H, W) layouts for this scale's k and v slices.
template<int S>
__global__ __launch_bounds__(256) void kv_proj(
    const float* __restrict__ x,
    const float* __restrict__ wk, const float* __restrict__ bk,
    const float* __restrict__ wv, const float* __restrict__ bv,
    float* __restrict__ ko, float* __restrict__ vo)
{
  const int img = blockIdx.y;
  const int p0  = blockIdx.x * 128;
  __shared__ float wl[32][68];    // [cc][o]  o<32: k-row, o>=32: v-row
  __shared__ float xl[32][132];   // [cc][p]
  const int tid = threadIdx.x;
  const int og = tid >> 4, pg = tid & 15;   // 16 groups x 4 o ; 16 groups x 8 px
  float acc[4][8];
  #pragma unroll
  for (int i=0;i<4;i++)
    #pragma unroll
    for (int j=0;j<8;j++) acc[i][j]=0.f;
  const float* xb = x + (size_t)img*IMG + p0;

  for (int k0=0; k0<128; k0+=32) {
    for (int idx=tid; idx<64*32; idx+=256) {
      int o = idx >> 5, cc = idx & 31;
      const float* wm = (o < 32) ? (wk + (size_t)(32*S + o)*128)
                                 : (wv + (size_t)(32*S + o - 32)*128);
      wl[cc][o] = wm[k0 + cc];
    }
    for (int idx=tid; idx<32*128; idx+=256) {
      int cc = idx >> 7, p = idx & 127;
      xl[cc][p] = xb[(size_t)(k0+cc)*HWP + p];
    }
    __syncthreads();
    #pragma unroll
    for (int cc=0; cc<32; cc++) {
      float4 wf = *(const float4*)&wl[cc][og*4];
      float4 xf0 = *(const float4*)&xl[cc][pg*8];
      float4 xf1 = *(const float4*)&xl[cc][pg*8+4];
      float wr[4] = {wf.x,wf.y,wf.z,wf.w};
      float xv8[8] = {xf0.x,xf0.y,xf0.z,xf0.w,xf1.x,xf1.y,xf1.z,xf1.w};
      #pragma unroll
      for (int i=0;i<4;i++)
        #pragma unroll
        for (int j=0;j<8;j++) acc[i][j] += wr[i]*xv8[j];
    }
    __syncthreads();
  }
  #pragma unroll
  for (int i=0;i<4;i++) {
    int o = og*4 + i;
    float bs; float* dst;
    if (o < 32) { bs = bk[32*S + o];      dst = ko + ((size_t)img*32 + o)*HWP      + p0 + pg*8; }
    else        { bs = bv[32*S + o - 32]; dst = vo + ((size_t)img*32 + o - 32)*HWP + p0 + pg*8; }
    float4 r0 = {acc[i][0]+bs, acc[i][1]+bs, acc[i][2]+bs, acc[i][3]+bs};
    float4 r1 = {acc[i][4]+bs, acc[i][5]+bs, acc[i][6]+bs, acc[i][7]+bs};
    *(float4*)dst       = r0;
    *(float4*)(dst + 4) = r1;
  }
}

// ---------------- 2a) scores, scale 0 (n=8, d=524288) ---------------------
__global__ __launch_bounds__(64) void scores_s0(
    const float* __restrict__ q, const float* __restrict__ kk,
    float* __restrict__ sc)
{
  constexpr int KC = 512;
  __shared__ float ql[8][KC+4], kl[8][KC+4];
  const int b  = blockIdx.y;
  const int k0 = blockIdx.x * KC;
  const int tid = threadIdx.x;
  for (int idx=tid; idx<8*KC; idx+=64) {
    int w = idx >> 9, c = idx & (KC-1);
    int f = k0 + c;
    int ch = f >> 14, r2 = f & 16383;
    ql[w][c] = q [((size_t)((b*TT + w)*NC + ch))*HWP + r2];   // q slice: ch 0..31
    kl[w][c] = kk[((size_t)((b*TT + w)*32 + ch))*HWP + r2];   // compact k
  }
  __syncthreads();
  const int nn = tid >> 3, mm = tid & 7;
  float acc = 0.f;
  #pragma unroll 8
  for (int c=0; c<KC; c+=4) {
    float4 qf = *(const float4*)&ql[nn][c];
    float4 kf = *(const float4*)&kl[mm][c];
    acc += qf.x*kf.x + qf.y*kf.y + qf.z*kf.z + qf.w*kf.w;
  }
  atomicAdd(&sc[(b*8 + nn)*8 + mm], acc);
}

// ---------------- 2b) scores, scales 1..3 (tiled gather-GEMM) -------------
template<int S, int TILE>
__global__ __launch_bounds__(256) void scores_gemm(
    const float* __restrict__ q, const float* __restrict__ kmat,
    float* __restrict__ sc, int kchunk)
{
  constexpr int TS = TILE/16;
  constexpr int KC = 64;
  constexpr int NT = SCg<S>::N / TILE;
  __shared__ float ql[TILE][KC+2], kl[TILE][KC+2];
  const int b  = blockIdx.z;
  const int tn = blockIdx.y / NT, tm = blockIdx.y % NT;
  const int tid = threadIdx.x;
  const int rg = tid >> 4, cg = tid & 15;
  float acc[TS][TS];
  #pragma unroll
  for (int i=0;i<TS;i++)
    #pragma unroll
    for (int j=0;j<TS;j++) acc[i][j]=0.f;
  const int k0b = blockIdx.x * kchunk;

  for (int k0=k0b; k0<k0b+kchunk; k0+=KC) {
    for (int idx=tid; idx<TILE*KC; idx+=256) {
      int r = idx >> 6, c = idx & 63;
      ql[r][c] = q   [win_addr<S,128,32*S>(b, tn*TILE + r, k0 + c)];
      kl[r][c] = kmat[win_addr<S,32,0>   (b, tm*TILE + r, k0 + c)];
    }
    __syncthreads();
    #pragma unroll 8
    for (int c=0; c<KC; c+=2) {
      float2 qf[TS], kf[TS];
      #pragma unroll
      for (int i=0;i<TS;i++) qf[i] = *(const float2*)&ql[rg*TS+i][c];
      #pragma unroll
      for (int j=0;j<TS;j++) kf[j] = *(const float2*)&kl[cg*TS+j][c];
      #pragma unroll
      for (int i=0;i<TS;i++)
        #pragma unroll
        for (int j=0;j<TS;j++)
          acc[i][j] += qf[i].x*kf[j].x + qf[i].y*kf[j].y;
    }
    __syncthreads();
  }
  #pragma unroll
  for (int i=0;i<TS;i++)
    #pragma unroll
    for (int j=0;j<TS;j++)
      atomicAdd(&sc[((size_t)b*SCg<S>::N + tn*TILE + rg*TS + i)*SCg<S>::N
                    + tm*TILE + cg*TS + j], acc[i][j]);
}

// ---------------- 3) softmax over rows -----------------------------------
__global__ __launch_bounds__(256) void softmax_rows(
    float* __restrict__ s, int n, float rsd)
{
  __shared__ float red[256];
  float* p = s + (size_t)blockIdx.x * n;
  const int tid = threadIdx.x;
  float lm = -1e30f;
  for (int j=tid;j<n;j+=256) lm = fmaxf(lm, p[j]*rsd);
  red[tid]=lm; __syncthreads();
  for (int st=128; st>0; st>>=1) { if (tid<st) red[tid]=fmaxf(red[tid],red[tid+st]); __syncthreads(); }
  const float mx = red[0]; __syncthreads();
  float ls = 0.f;
  for (int j=tid;j<n;j+=256) { float e = expf(p[j]*rsd - mx); p[j]=e; ls+=e; }
  red[tid]=ls; __syncthreads();
  for (int st=128; st>0; st>>=1) { if (tid<st) red[tid]+=red[tid+st]; __syncthreads(); }
  const float inv = 1.f/red[0];
  for (int j=tid;j<n;j+=256) p[j]*=inv;
}

// ---------------- 4a) PV, scale 0 -----------------------------------------
__global__ __launch_bounds__(256) void pv_s0(
    const float* __restrict__ attn, const float* __restrict__ v,
    float* __restrict__ y)
{
  __shared__ float al[8][8];
  const int b = blockIdx.y;
  const int tid = threadIdx.x;
  if (tid < 64) al[tid>>3][tid&7] = attn[b*64 + tid];
  __syncthreads();
  const int f  = blockIdx.x*256 + tid;
  const int c  = f >> 14;
  const int r2 = f & 16383;
  float acc[8];
  #pragma unroll
  for (int i=0;i<8;i++) acc[i]=0.f;
  #pragma unroll
  for (int m=0;m<8;m++) {
    float vv = v[((size_t)((b*TT+m)*32 + c))*HWP + r2];       // compact v
    #pragma unroll
    for (int nn=0;nn<8;nn++) acc[nn] += al[nn][m]*vv;
  }
  #pragma unroll
  for (int nn=0;nn<8;nn++)
    y[((size_t)((b*TT+nn)*NC + c))*HWP + r2] = acc[nn];       // y -> q ch 0..31
}

// ---------------- 4b) PV, scales 1..3 -------------------------------------
template<int S>
__global__ __launch_bounds__(256) void pv_gemm(
    const float* __restrict__ attn, const float* __restrict__ v,
    float* __restrict__ y)
{
  constexpr int N_ = SCg<S>::N;
  constexpr int TN = (N_ < 128) ? N_ : 128;
  constexpr int WSB = TN/16;
  constexpr int KM = 32, TF = 64;
  __shared__ float al[KM][TN+4];
  __shared__ float vl[KM][TF+4];
  const int b  = blockIdx.z;
  const int w0 = blockIdx.y * TN;
  const int f0 = blockIdx.x * TF;
  const int tid = threadIdx.x;
  const int wg = tid >> 4, fg = tid & 15;
  float acc[WSB][4];
  #pragma unroll
  for (int i=0;i<WSB;i++)
    #pragma unroll
    for (int j=0;j<4;j++) acc[i][j]=0.f;

  for (int m0=0; m0<N_; m0+=KM) {
    for (int idx=tid; idx<KM*TN; idx+=256) {
      int mm = idx / TN, ww = idx % TN;
      al[mm][ww] = attn[((size_t)b*N_ + w0 + ww)*N_ + m0 + mm];
    }
    for (int idx=tid; idx<KM*TF; idx+=256) {
      int mm = idx >> 6, ff = idx & 63;
      vl[mm][ff] = v[win_addr<S,32,0>(b, m0 + mm, f0 + ff)];
    }
    __syncthreads();
    #pragma unroll
    for (int mm=0; mm<KM; mm++) {
      float4 vf = *(const float4*)&vl[mm][fg*4];
      #pragma unroll
      for (int i=0;i<WSB;i++) {
        float a = al[mm][wg*WSB + i];
        acc[i][0] += a*vf.x; acc[i][1] += a*vf.y;
        acc[i][2] += a*vf.z; acc[i][3] += a*vf.w;
      }
    }
    __syncthreads();
  }
  #pragma unroll
  for (int i=0;i<WSB;i++) {
    float4 r = {acc[i][0], acc[i][1], acc[i][2], acc[i][3]};
    *(float4*)&y[win_addr<S,128,32*S>(b, w0 + wg*WSB + i, f0 + fg*4)] = r;
  }
}

// ---------------- 5) 3x3 SAME conv + bias + ReLU --------------------------
__global__ __launch_bounds__(256) void conv3x3(
    const float* __restrict__ yin, const float* __restrict__ wo,
    const float* __restrict__ bo, float* __restrict__ out)
{
  __shared__ float wl[3][32][68];   // [kx][cc][o]  (one ky at a time)
  __shared__ float xl[32][132];     // [cc][j] = input col j-1; cols -1 & 128 const 0
  const int img  = blockIdx.z;
  const int o0   = blockIdx.y * 64;
  const int yrow = blockIdx.x;
  const int tid = threadIdx.x;
  const int og = tid >> 4, pg = tid & 15;   // 4 o x 8 px per thread
  float acc[4][8];
  #pragma unroll
  for (int i=0;i<4;i++)
    #pragma unroll
    for (int j=0;j<8;j++) acc[i][j]=0.f;

  // halo columns (image cols -1 and 128) are always zero-padded; set once.
  if (tid < 64) xl[tid>>1][(tid&1) ? 129 : 0] = 0.f;

  for (int ky=0; ky<3; ky++) {
    const int yy = yrow + ky - 1;
    const bool rowok = (yy >= 0) && (yy < HH);
    const float* rowbase = yin + (size_t)img*NC*HWP + (size_t)yy*WW;
    for (int c0=0; c0<128; c0+=32) {
      // weights: 3*64*32 = 6144 elems, pure shift/mask indexing
      for (int idx=tid; idx<3*64*32; idx+=256) {
        int kx = idx >> 11, rem = idx & 2047;
        int o = rem >> 5, cc = rem & 31;
        wl[kx][cc][o] = wo[((size_t)(o0+o)*128 + c0 + cc)*9 + ky*3 + kx];
      }
      // input row: 32 chans x 128 cols, shift/mask indexing (halo is const 0)
      for (int idx=tid; idx<32*128; idx+=256) {
        int cc = idx >> 7, p = idx & 127;
        xl[cc][p+1] = rowok ? rowbase[(size_t)(c0+cc)*HWP + p] : 0.f;
      }
      __syncthreads();
      #pragma unroll 4
      for (int cc=0; cc<32; cc++) {
        float xv[10];
        #pragma unroll
        for (int j=0;j<10;j++) xv[j] = xl[cc][pg*8 + j];
        #pragma unroll
        for (int kx=0;kx<3;kx++) {
          float4 wf = *(const float4*)&wl[kx][cc][og*4];
          float wr[4] = {wf.x, wf.y, wf.z, wf.w};
          #pragma unroll
          for (int i=0;i<4;i++)
            #pragma unroll
            for (int j=0;j<8;j++)
              acc[i][j] += wr[i]*xv[j+kx];
        }
      }
      __syncthreads();
    }
  }
  #pragma unroll
  for (int i=0;i<4;i++) {
    const int o = o0 + og*4 + i;
    const float bs = bo[o];
    float* dst = out + ((size_t)img*NC + o)*HWP + yrow*WW + pg*8;
    float4 r0, r1;
    r0.x = fmaxf(acc[i][0]+bs, 0.f); r0.y = fmaxf(acc[i][1]+bs, 0.f);
    r0.z = fmaxf(acc[i][2]+bs, 0.f); r0.w = fmaxf(acc[i][3]+bs, 0.f);
    r1.x = fmaxf(acc[i][4]+bs, 0.f); r1.y = fmaxf(acc[i][5]+bs, 0.f);
    r1.z = fmaxf(acc[i][6]+bs, 0.f); r1.w = fmaxf(acc[i][7]+bs, 0.f);
    *(float4*)dst       = r0;
    *(float4*)(dst + 4) = r1;
  }
}

// ---------------- launcher -------------------------------------------------
extern "C" void kernel_launch(void* const* d_in, const int* in_sizes, int n_in,
                              void* d_out, int out_size, void* d_ws, size_t ws_size,
                              hipStream_t stream) {
  const float* x  = (const float*)d_in[0];
  const float* wq = (const float*)d_in[1];
  const float* bq = (const float*)d_in[2];
  const float* wk = (const float*)d_in[3];
  const float* bk = (const float*)d_in[4];
  const float* wv = (const float*)d_in[5];
  const float* bv = (const float*)d_in[6];
  const float* wo = (const float*)d_in[7];
  const float* bo = (const float*)d_in[8];
  float* out = (float*)d_out;

  // workspace layout (floats): q 33,554,432 | k 8,388,608 | v 8,388,608 | sc 524,288
  // total 50,855,936 floats = 203.4 MB
  float* q    = (float*)d_ws;
  float* kbuf = q    + 33554432ull;
  float* vbuf = kbuf + 8388608ull;
  float* sc   = vbuf + 8388608ull;

  // 1) Q projection (all channels)
  q_proj<<<dim3(128,16), 256, 0, stream>>>(x, wq, bq, q);

  // ---- scale 0: n=8, d=524288 ----
  kv_proj<0><<<dim3(128,16), 256, 0, stream>>>(x, wk,bk, wv,bv, kbuf, vbuf);
  hipMemsetAsync(sc, 0, (size_t)2*8*8*sizeof(float), stream);
  scores_s0<<<dim3(1024,2), 64, 0, stream>>>(q, kbuf, sc);
  softmax_rows<<<2*8, 256, 0, stream>>>(sc, 8, 1.0f/sqrtf(524288.f));
  pv_s0<<<dim3(2048,2), 256, 0, stream>>>(sc, vbuf, q);   // y slice 0 -> q ch 0..31

  // ---- scale 1: n=32, d=131072 ----
  kv_proj<1><<<dim3(128,16), 256, 0, stream>>>(x, wk,bk, wv,bv, kbuf, vbuf);
  hipMemsetAsync(sc, 0, (size_t)2*32*32*sizeof(float), stream);
  scores_gemm<1,32><<<dim3(256,1,2), 256, 0, stream>>>(q, kbuf, sc, 512);
  softmax_rows<<<2*32, 256, 0, stream>>>(sc, 32, 1.0f/sqrtf(131072.f));
  pv_gemm<1><<<dim3(131072/64, 1, 2), 256, 0, stream>>>(sc, vbuf, q);

  // ---- scale 2: n=128, d=32768 ----
  kv_proj<2><<<dim3(128,16), 256, 0, stream>>>(x, wk,bk, wv,bv, kbuf, vbuf);
  hipMemsetAsync(sc, 0, (size_t)2*128*128*sizeof(float), stream);
  scores_gemm<2,64><<<dim3(64,4,2), 256, 0, stream>>>(q, kbuf, sc, 512);
  softmax_rows<<<2*128, 256, 0, stream>>>(sc, 128, 1.0f/sqrtf(32768.f));
  pv_gemm<2><<<dim3(32768/64, 1, 2), 256, 0, stream>>>(sc, vbuf, q);

  // ---- scale 3: n=512, d=8192 ----
  kv_proj<3><<<dim3(128,16), 256, 0, stream>>>(x, wk,bk, wv,bv, kbuf, vbuf);
  hipMemsetAsync(sc, 0, (size_t)2*512*512*sizeof(float), stream);
  scores_gemm<3,64><<<dim3(4,64,2), 256, 0, stream>>>(q, kbuf, sc, 2048);
  softmax_rows<<<2*512, 256, 0, stream>>>(sc, 512, 1.0f/sqrtf(8192.f));
  pv_gemm<3><<<dim3(8192/64, 4, 2), 256, 0, stream>>>(sc, vbuf, q);

  // 6) 3x3 conv + bias + relu (reads attention output from q buffer)
  conv3x3<<<dim3(128, 2, 16), 256, 0, stream>>>(q, wo, bo, out);
}

// Round 6
// 1899.559 us; speedup vs baseline: 1.4993x; 1.4993x over previous
//
#include <hip/hip_runtime.h>
#include <math.h>

#define TT 8
#define NC 128
#define HH 128
#define WW 128
#define HWP (HH*WW)
#define IMG ((size_t)NC*HWP)

typedef __attribute__((ext_vector_type(8))) short bf16x8;
typedef __attribute__((ext_vector_type(4))) float f32x4;

__device__ __forceinline__ unsigned short f2bf_rn(float f) {
  unsigned u = __builtin_bit_cast(unsigned, f);
  unsigned r = u + 0x7FFFu + ((u >> 16) & 1u);
  return (unsigned short)(r >> 16);
}
__device__ __forceinline__ float bf2f(unsigned short h) {
  unsigned u = ((unsigned)h) << 16;
  return __builtin_bit_cast(float, u);
}

// ---------------- per-scale compile-time geometry ----------------
template<int S> struct SCg {
  static constexpr int PH   = 128 >> S;
  static constexpr int OH   = 1 << S;
  static constexpr int OHOW = OH*OH;
  static constexpr int N    = TT*OHOW;
  static constexpr int PHPW = PH*PH;
  static constexpr int D    = 32*PHPW;
  static constexpr int LPW  = 7 - S;
  static constexpr int LPP  = 14 - 2*S;
};

template<int S, int CS, int CB0>
__device__ __forceinline__ size_t win_addr(int b, int w, int f) {
  int t  = w >> (2*S);
  int rr = w & (SCg<S>::OHOW-1);
  int oy = rr >> S;
  int ox = rr & (SCg<S>::OH-1);
  int c  = f >> SCg<S>::LPP;
  int r2 = f & (SCg<S>::PHPW-1);
  int py = r2 >> SCg<S>::LPW;
  int px = r2 & (SCg<S>::PH-1);
  return ((size_t)((b*TT + t)*CS + CB0 + c))*HWP
       + (size_t)((oy*SCg<S>::PH + py)*WW) + ox*SCg<S>::PH + px;
}

// ---------------- 1a) Q projection (1x1 conv, all 128 channels) ----------
__global__ __launch_bounds__(256) void q_proj(
    const float* __restrict__ x,
    const float* __restrict__ wq, const float* __restrict__ bq,
    float* __restrict__ q)
{
  const int img = blockIdx.y;
  const int p0  = blockIdx.x * 128;
  __shared__ float wl[32][132];
  __shared__ float xl[32][132];
  const int tid = threadIdx.x;
  const int og = tid >> 4, pg = tid & 15;
  float acc[8][8];
  #pragma unroll
  for (int i=0;i<8;i++)
    #pragma unroll
    for (int j=0;j<8;j++) acc[i][j]=0.f;
  const float* xb = x + (size_t)img*IMG + p0;

  for (int k0=0; k0<128; k0+=32) {
    for (int idx=tid; idx<32*128; idx+=256) {
      int o = idx >> 5, cc = idx & 31;
      wl[cc][o] = wq[o*128 + k0 + cc];
    }
    for (int idx=tid; idx<32*128; idx+=256) {
      int cc = idx >> 7, p = idx & 127;
      xl[cc][p] = xb[(size_t)(k0+cc)*HWP + p];
    }
    __syncthreads();
    #pragma unroll
    for (int cc=0; cc<32; cc++) {
      float4 wf0 = *(const float4*)&wl[cc][og*8];
      float4 wf1 = *(const float4*)&wl[cc][og*8+4];
      float4 xf0 = *(const float4*)&xl[cc][pg*8];
      float4 xf1 = *(const float4*)&xl[cc][pg*8+4];
      float wv8[8] = {wf0.x,wf0.y,wf0.z,wf0.w,wf1.x,wf1.y,wf1.z,wf1.w};
      float xv8[8] = {xf0.x,xf0.y,xf0.z,xf0.w,xf1.x,xf1.y,xf1.z,xf1.w};
      #pragma unroll
      for (int i=0;i<8;i++)
        #pragma unroll
        for (int j=0;j<8;j++) acc[i][j] += wv8[i]*xv8[j];
    }
    __syncthreads();
  }
  #pragma unroll
  for (int i=0;i<8;i++) {
    int o = og*8 + i;
    float bs = bq[o];
    float* dst = q + ((size_t)img*NC + o)*HWP + p0 + pg*8;
    float4 r0 = {acc[i][0]+bs, acc[i][1]+bs, acc[i][2]+bs, acc[i][3]+bs};
    float4 r1 = {acc[i][4]+bs, acc[i][5]+bs, acc[i][6]+bs, acc[i][7]+bs};
    *(float4*)dst       = r0;
    *(float4*)(dst + 4) = r1;
  }
}

// ---------------- 1b) per-scale K,V slice projection ---------------------
template<int S>
__global__ __launch_bounds__(256) void kv_proj(
    const float* __restrict__ x,
    const float* __restrict__ wk, const float* __restrict__ bk,
    const float* __restrict__ wv, const float* __restrict__ bv,
    float* __restrict__ ko, float* __restrict__ vo)
{
  const int img = blockIdx.y;
  const int p0  = blockIdx.x * 128;
  __shared__ float wl[32][68];
  __shared__ float xl[32][132];
  const int tid = threadIdx.x;
  const int og = tid >> 4, pg = tid & 15;
  float acc[4][8];
  #pragma unroll
  for (int i=0;i<4;i++)
    #pragma unroll
    for (int j=0;j<8;j++) acc[i][j]=0.f;
  const float* xb = x + (size_t)img*IMG + p0;

  for (int k0=0; k0<128; k0+=32) {
    for (int idx=tid; idx<64*32; idx+=256) {
      int o = idx >> 5, cc = idx & 31;
      const float* wm = (o < 32) ? (wk + (size_t)(32*S + o)*128)
                                 : (wv + (size_t)(32*S + o - 32)*128);
      wl[cc][o] = wm[k0 + cc];
    }
    for (int idx=tid; idx<32*128; idx+=256) {
      int cc = idx >> 7, p = idx & 127;
      xl[cc][p] = xb[(size_t)(k0+cc)*HWP + p];
    }
    __syncthreads();
    #pragma unroll
    for (int cc=0; cc<32; cc++) {
      float4 wf = *(const float4*)&wl[cc][og*4];
      float4 xf0 = *(const float4*)&xl[cc][pg*8];
      float4 xf1 = *(const float4*)&xl[cc][pg*8+4];
      float wr[4] = {wf.x,wf.y,wf.z,wf.w};
      float xv8[8] = {xf0.x,xf0.y,xf0.z,xf0.w,xf1.x,xf1.y,xf1.z,xf1.w};
      #pragma unroll
      for (int i=0;i<4;i++)
        #pragma unroll
        for (int j=0;j<8;j++) acc[i][j] += wr[i]*xv8[j];
    }
    __syncthreads();
  }
  #pragma unroll
  for (int i=0;i<4;i++) {
    int o = og*4 + i;
    float bs; float* dst;
    if (o < 32) { bs = bk[32*S + o];      dst = ko + ((size_t)img*32 + o)*HWP      + p0 + pg*8; }
    else        { bs = bv[32*S + o - 32]; dst = vo + ((size_t)img*32 + o - 32)*HWP + p0 + pg*8; }
    float4 r0 = {acc[i][0]+bs, acc[i][1]+bs, acc[i][2]+bs, acc[i][3]+bs};
    float4 r1 = {acc[i][4]+bs, acc[i][5]+bs, acc[i][6]+bs, acc[i][7]+bs};
    *(float4*)dst       = r0;
    *(float4*)(dst + 4) = r1;
  }
}

// ---------------- 2a) scores, scale 0 ------------------------------------
__global__ __launch_bounds__(64) void scores_s0(
    const float* __restrict__ q, const float* __restrict__ kk,
    float* __restrict__ sc)
{
  constexpr int KC = 512;
  __shared__ float ql[8][KC+4], kl[8][KC+4];
  const int b  = blockIdx.y;
  const int k0 = blockIdx.x * KC;
  const int tid = threadIdx.x;
  for (int idx=tid; idx<8*KC; idx+=64) {
    int w = idx >> 9, c = idx & (KC-1);
    int f = k0 + c;
    int ch = f >> 14, r2 = f & 16383;
    ql[w][c] = q [((size_t)((b*TT + w)*NC + ch))*HWP + r2];
    kl[w][c] = kk[((size_t)((b*TT + w)*32 + ch))*HWP + r2];
  }
  __syncthreads();
  const int nn = tid >> 3, mm = tid & 7;
  float acc = 0.f;
  #pragma unroll 8
  for (int c=0; c<KC; c+=4) {
    float4 qf = *(const float4*)&ql[nn][c];
    float4 kf = *(const float4*)&kl[mm][c];
    acc += qf.x*kf.x + qf.y*kf.y + qf.z*kf.z + qf.w*kf.w;
  }
  atomicAdd(&sc[(b*8 + nn)*8 + mm], acc);
}

// ---------------- 2b) scores, scales 1..3 --------------------------------
template<int S, int TILE>
__global__ __launch_bounds__(256) void scores_gemm(
    const float* __restrict__ q, const float* __restrict__ kmat,
    float* __restrict__ sc, int kchunk)
{
  constexpr int TS = TILE/16;
  constexpr int KC = 64;
  constexpr int NT = SCg<S>::N / TILE;
  __shared__ float ql[TILE][KC+2], kl[TILE][KC+2];
  const int b  = blockIdx.z;
  const int tn = blockIdx.y / NT, tm = blockIdx.y % NT;
  const int tid = threadIdx.x;
  const int rg = tid >> 4, cg = tid & 15;
  float acc[TS][TS];
  #pragma unroll
  for (int i=0;i<TS;i++)
    #pragma unroll
    for (int j=0;j<TS;j++) acc[i][j]=0.f;
  const int k0b = blockIdx.x * kchunk;

  for (int k0=k0b; k0<k0b+kchunk; k0+=KC) {
    for (int idx=tid; idx<TILE*KC; idx+=256) {
      int r = idx >> 6, c = idx & 63;
      ql[r][c] = q   [win_addr<S,128,32*S>(b, tn*TILE + r, k0 + c)];
      kl[r][c] = kmat[win_addr<S,32,0>   (b, tm*TILE + r, k0 + c)];
    }
    __syncthreads();
    #pragma unroll 8
    for (int c=0; c<KC; c+=2) {
      float2 qf[TS], kf[TS];
      #pragma unroll
      for (int i=0;i<TS;i++) qf[i] = *(const float2*)&ql[rg*TS+i][c];
      #pragma unroll
      for (int j=0;j<TS;j++) kf[j] = *(const float2*)&kl[cg*TS+j][c];
      #pragma unroll
      for (int i=0;i<TS;i++)
        #pragma unroll
        for (int j=0;j<TS;j++)
          acc[i][j] += qf[i].x*kf[j].x + qf[i].y*kf[j].y;
    }
    __syncthreads();
  }
  #pragma unroll
  for (int i=0;i<TS;i++)
    #pragma unroll
    for (int j=0;j<TS;j++)
      atomicAdd(&sc[((size_t)b*SCg<S>::N + tn*TILE + rg*TS + i)*SCg<S>::N
                    + tm*TILE + cg*TS + j], acc[i][j]);
}

// ---------------- 3) softmax over rows -----------------------------------
__global__ __launch_bounds__(256) void softmax_rows(
    float* __restrict__ s, int n, float rsd)
{
  __shared__ float red[256];
  float* p = s + (size_t)blockIdx.x * n;
  const int tid = threadIdx.x;
  float lm = -1e30f;
  for (int j=tid;j<n;j+=256) lm = fmaxf(lm, p[j]*rsd);
  red[tid]=lm; __syncthreads();
  for (int st=128; st>0; st>>=1) { if (tid<st) red[tid]=fmaxf(red[tid],red[tid+st]); __syncthreads(); }
  const float mx = red[0]; __syncthreads();
  float ls = 0.f;
  for (int j=tid;j<n;j+=256) { float e = expf(p[j]*rsd - mx); p[j]=e; ls+=e; }
  red[tid]=ls; __syncthreads();
  for (int st=128; st>0; st>>=1) { if (tid<st) red[tid]+=red[tid+st]; __syncthreads(); }
  const float inv = 1.f/red[0];
  for (int j=tid;j<n;j+=256) p[j]*=inv;
}

// ---------------- 4a) PV, scale 0 -----------------------------------------
__global__ __launch_bounds__(256) void pv_s0(
    const float* __restrict__ attn, const float* __restrict__ v,
    float* __restrict__ y)
{
  __shared__ float al[8][8];
  const int b = blockIdx.y;
  const int tid = threadIdx.x;
  if (tid < 64) al[tid>>3][tid&7] = attn[b*64 + tid];
  __syncthreads();
  const int f  = blockIdx.x*256 + tid;
  const int c  = f >> 14;
  const int r2 = f & 16383;
  float acc[8];
  #pragma unroll
  for (int i=0;i<8;i++) acc[i]=0.f;
  #pragma unroll
  for (int m=0;m<8;m++) {
    float vv = v[((size_t)((b*TT+m)*32 + c))*HWP + r2];
    #pragma unroll
    for (int nn=0;nn<8;nn++) acc[nn] += al[nn][m]*vv;
  }
  #pragma unroll
  for (int nn=0;nn<8;nn++)
    y[((size_t)((b*TT+nn)*NC + c))*HWP + r2] = acc[nn];
}

// ---------------- 4b) PV, scales 1..3 -------------------------------------
template<int S>
__global__ __launch_bounds__(256) void pv_gemm(
    const float* __restrict__ attn, const float* __restrict__ v,
    float* __restrict__ y)
{
  constexpr int N_ = SCg<S>::N;
  constexpr int TN = (N_ < 128) ? N_ : 128;
  constexpr int WSB = TN/16;
  constexpr int KM = 32, TF = 64;
  __shared__ float al[KM][TN+4];
  __shared__ float vl[KM][TF+4];
  const int b  = blockIdx.z;
  const int w0 = blockIdx.y * TN;
  const int f0 = blockIdx.x * TF;
  const int tid = threadIdx.x;
  const int wg = tid >> 4, fg = tid & 15;
  float acc[WSB][4];
  #pragma unroll
  for (int i=0;i<WSB;i++)
    #pragma unroll
    for (int j=0;j<4;j++) acc[i][j]=0.f;

  for (int m0=0; m0<N_; m0+=KM) {
    for (int idx=tid; idx<KM*TN; idx+=256) {
      int mm = idx / TN, ww = idx % TN;
      al[mm][ww] = attn[((size_t)b*N_ + w0 + ww)*N_ + m0 + mm];
    }
    for (int idx=tid; idx<KM*TF; idx+=256) {
      int mm = idx >> 6, ff = idx & 63;
      vl[mm][ff] = v[win_addr<S,32,0>(b, m0 + mm, f0 + ff)];
    }
    __syncthreads();
    #pragma unroll
    for (int mm=0; mm<KM; mm++) {
      float4 vf = *(const float4*)&vl[mm][fg*4];
      #pragma unroll
      for (int i=0;i<WSB;i++) {
        float a = al[mm][wg*WSB + i];
        acc[i][0] += a*vf.x; acc[i][1] += a*vf.y;
        acc[i][2] += a*vf.z; acc[i][3] += a*vf.w;
      }
    }
    __syncthreads();
  }
  #pragma unroll
  for (int i=0;i<WSB;i++) {
    float4 r = {acc[i][0], acc[i][1], acc[i][2], acc[i][3]};
    *(float4*)&y[win_addr<S,128,32*S>(b, w0 + wg*WSB + i, f0 + fg*4)] = r;
  }
}

// ---------------- 5a) pack conv weights -> [tap][o][c] bf16 hi/lo ---------
__global__ __launch_bounds__(256) void pack_w(
    const float* __restrict__ wo,
    unsigned short* __restrict__ whi, unsigned short* __restrict__ wlo)
{
  int idx = blockIdx.x*256 + threadIdx.x;
  if (idx >= 9*128*128) return;
  int c = idx & 127, o = (idx >> 7) & 127, tap = idx >> 14;
  float f = wo[((size_t)o*128 + c)*9 + tap];
  unsigned short h = f2bf_rn(f);
  whi[idx] = h;
  wlo[idx] = f2bf_rn(f - bf2f(h));
}

// ---------------- 5b) pack attention output -> [img][row][px][c] hi/lo ----
__global__ __launch_bounds__(256) void pack_y(
    const float* __restrict__ y,
    unsigned short* __restrict__ yth, unsigned short* __restrict__ ytl)
{
  __shared__ float tl[32][130];
  const int row = blockIdx.x, img = blockIdx.y;
  const int tid = threadIdx.x;
  for (int c0=0; c0<128; c0+=32) {
    __syncthreads();
    #pragma unroll
    for (int e=0; e<16; ++e) {
      int idx = e*256 + tid;
      int cc = idx >> 7, px = idx & 127;
      tl[cc][px] = y[((size_t)img*NC + c0+cc)*HWP + row*WW + px];
    }
    __syncthreads();
    #pragma unroll
    for (int e=0; e<16; ++e) {
      int idx = e*256 + tid;
      int px = idx >> 5, cc = idx & 31;
      float f = tl[cc][px];
      unsigned short h = f2bf_rn(f);
      size_t oa = (((size_t)img*HH + row)*WW + px)*NC + c0 + cc;
      yth[oa] = h;
      ytl[oa] = f2bf_rn(f - bf2f(h));
    }
  }
}

// ---------------- 5c) 3x3 conv via MFMA (split-bf16, 3-term) --------------
// block: 64 o x 128 px (one output row); 4 waves, wave w -> o-tile w*16..+15.
__global__ __launch_bounds__(256) void conv3x3_mfma(
    const unsigned short* __restrict__ yth, const unsigned short* __restrict__ ytl,
    const unsigned short* __restrict__ whi, const unsigned short* __restrict__ wlo,
    const float* __restrict__ bo, float* __restrict__ out)
{
  constexpr int XP = 40;                  // padded LDS row (ushorts) = 80 B
  __shared__ unsigned short xh[130*XP], xlo[130*XP];   // input  [px+1][c]
  __shared__ unsigned short wh[3*64*XP], wl2[3*64*XP]; // weights [kx][o][c]
  const int yrow = blockIdx.x, ob = blockIdx.y, img = blockIdx.z;
  const int o0 = ob*64;
  const int tid = threadIdx.x;
  const int lane = tid & 63, wave = tid >> 6;
  const int lrow = lane & 15, lk = lane >> 4;

  f32x4 acc[8];
  #pragma unroll
  for (int j=0;j<8;++j) acc[j] = (f32x4){0.f,0.f,0.f,0.f};

  // zero halo rows (px=-1 and px=128); never overwritten by stages
  if (tid < 80) {
    int off = (tid < 40) ? tid : 129*XP + (tid-40);
    xh[off] = 0; xlo[off] = 0;
  }

  for (int ky=0; ky<3; ++ky) {
    const int yy = yrow + ky - 1;
    if (yy < 0 || yy >= HH) continue;    // block-uniform
    const unsigned short* ysh = yth + (((size_t)img*HH + yy)*WW)*NC;
    const unsigned short* ysl = ytl + (((size_t)img*HH + yy)*WW)*NC;
    for (int c0=0; c0<128; c0+=32) {
      __syncthreads();                   // previous tile fully consumed
      // stage input: 128 px x 32 c, 16B chunks (px = tid>>2, oct = tid&3)
      #pragma unroll
      for (int it=0; it<2; ++it) {
        int px = (tid >> 2) + it*64;
        int oc = tid & 3;
        const uint4 hv = *(const uint4*)(ysh + (size_t)px*NC + c0 + oc*8);
        const uint4 lv = *(const uint4*)(ysl + (size_t)px*NC + c0 + oc*8);
        *(uint4*)&xh [(px+1)*XP + oc*8] = hv;
        *(uint4*)&xlo[(px+1)*XP + oc*8] = lv;
      }
      // stage weights: 3 kx x 64 o x 4 octs
      #pragma unroll
      for (int it=0; it<3; ++it) {
        int idx = it*256 + tid;          // 0..767
        int kx = idx >> 8, rem = idx & 255;
        int o = rem >> 2, oc = rem & 3;
        size_t ga = ((size_t)((ky*3+kx)*128) + o0 + o)*128 + c0 + oc*8;
        *(uint4*)&wh [(kx*64+o)*XP + oc*8] = *(const uint4*)(whi + ga);
        *(uint4*)&wl2[(kx*64+o)*XP + oc*8] = *(const uint4*)(wlo + ga);
      }
      __syncthreads();
      #pragma unroll
      for (int kx=0; kx<3; ++kx) {
        bf16x8 ah = *(bf16x8*)&wh [(kx*64 + wave*16 + lrow)*XP + lk*8];
        bf16x8 al = *(bf16x8*)&wl2[(kx*64 + wave*16 + lrow)*XP + lk*8];
        #pragma unroll
        for (int j=0;j<8;++j) {
          int r = j*16 + lrow + kx;      // xt row = px + kx (px index +1 baked in)
          bf16x8 bh = *(bf16x8*)&xh [r*XP + lk*8];
          bf16x8 bl = *(bf16x8*)&xlo[r*XP + lk*8];
          acc[j] = __builtin_amdgcn_mfma_f32_16x16x32_bf16(ah, bh, acc[j], 0,0,0);
          acc[j] = __builtin_amdgcn_mfma_f32_16x16x32_bf16(ah, bl, acc[j], 0,0,0);
          acc[j] = __builtin_amdgcn_mfma_f32_16x16x32_bf16(al, bh, acc[j], 0,0,0);
        }
      }
    }
  }
  // epilogue: C col = lane&15 (px), row = (lane>>4)*4 + i (o)
  float bs[4];
  #pragma unroll
  for (int i=0;i<4;++i) bs[i] = bo[o0 + wave*16 + lk*4 + i];
  #pragma unroll
  for (int j=0;j<8;++j) {
    #pragma unroll
    for (int i=0;i<4;++i) {
      int o = o0 + wave*16 + lk*4 + i;
      float r = fmaxf(acc[j][i] + bs[i], 0.f);
      out[((size_t)img*NC + o)*HWP + yrow*WW + j*16 + lrow] = r;
    }
  }
}

// ---------------- launcher -------------------------------------------------
extern "C" void kernel_launch(void* const* d_in, const int* in_sizes, int n_in,
                              void* d_out, int out_size, void* d_ws, size_t ws_size,
                              hipStream_t stream) {
  const float* x  = (const float*)d_in[0];
  const float* wq = (const float*)d_in[1];
  const float* bq = (const float*)d_in[2];
  const float* wk = (const float*)d_in[3];
  const float* bk = (const float*)d_in[4];
  const float* wv = (const float*)d_in[5];
  const float* bv = (const float*)d_in[6];
  const float* wo = (const float*)d_in[7];
  const float* bo = (const float*)d_in[8];
  float* out = (float*)d_out;

  // ws layout: q 134.2MB | k 33.6 | v 33.6 | sc 2.1 | whi/wlo 0.6 | yt hi/lo 134.2
  // total ~338.3 MB
  float* q    = (float*)d_ws;
  float* kbuf = q    + 33554432ull;
  float* vbuf = kbuf + 8388608ull;
  float* sc   = vbuf + 8388608ull;
  unsigned short* whi_ = (unsigned short*)(sc + 524288ull);
  unsigned short* wlo_ = whi_ + 147456ull;
  unsigned short* yth  = wlo_ + 147456ull;
  unsigned short* ytl  = yth  + 33554432ull;

  // 0) pack conv weights (independent)
  pack_w<<<576, 256, 0, stream>>>(wo, whi_, wlo_);

  // 1) Q projection (all channels)
  q_proj<<<dim3(128,16), 256, 0, stream>>>(x, wq, bq, q);

  // ---- scale 0 ----
  kv_proj<0><<<dim3(128,16), 256, 0, stream>>>(x, wk,bk, wv,bv, kbuf, vbuf);
  hipMemsetAsync(sc, 0, (size_t)2*8*8*sizeof(float), stream);
  scores_s0<<<dim3(1024,2), 64, 0, stream>>>(q, kbuf, sc);
  softmax_rows<<<2*8, 256, 0, stream>>>(sc, 8, 1.0f/sqrtf(524288.f));
  pv_s0<<<dim3(2048,2), 256, 0, stream>>>(sc, vbuf, q);

  // ---- scale 1 ----
  kv_proj<1><<<dim3(128,16), 256, 0, stream>>>(x, wk,bk, wv,bv, kbuf, vbuf);
  hipMemsetAsync(sc, 0, (size_t)2*32*32*sizeof(float), stream);
  scores_gemm<1,32><<<dim3(256,1,2), 256, 0, stream>>>(q, kbuf, sc, 512);
  softmax_rows<<<2*32, 256, 0, stream>>>(sc, 32, 1.0f/sqrtf(131072.f));
  pv_gemm<1><<<dim3(131072/64, 1, 2), 256, 0, stream>>>(sc, vbuf, q);

  // ---- scale 2 ----
  kv_proj<2><<<dim3(128,16), 256, 0, stream>>>(x, wk,bk, wv,bv, kbuf, vbuf);
  hipMemsetAsync(sc, 0, (size_t)2*128*128*sizeof(float), stream);
  scores_gemm<2,64><<<dim3(64,4,2), 256, 0, stream>>>(q, kbuf, sc, 512);
  softmax_rows<<<2*128, 256, 0, stream>>>(sc, 128, 1.0f/sqrtf(32768.f));
  pv_gemm<2><<<dim3(32768/64, 1, 2), 256, 0, stream>>>(sc, vbuf, q);

  // ---- scale 3 ----
  kv_proj<3><<<dim3(128,16), 256, 0, stream>>>(x, wk,bk, wv,bv, kbuf, vbuf);
  hipMemsetAsync(sc, 0, (size_t)2*512*512*sizeof(float), stream);
  scores_gemm<3,64><<<dim3(4,64,2), 256, 0, stream>>>(q, kbuf, sc, 2048);
  softmax_rows<<<2*512, 256, 0, stream>>>(sc, 512, 1.0f/sqrtf(8192.f));
  pv_gemm<3><<<dim3(8192/64, 4, 2), 256, 0, stream>>>(sc, vbuf, q);

  // 5) pack attention output (q buffer holds y, all 128 channels)
  pack_y<<<dim3(128,16), 256, 0, stream>>>(q, yth, ytl);

  // 6) 3x3 conv + bias + relu via MFMA
  conv3x3_mfma<<<dim3(128, 2, 16), 256, 0, stream>>>(yth, ytl, whi_, wlo_, bo, out);
}

// Round 8
// 1345.790 us; speedup vs baseline: 2.1163x; 1.4115x over previous
//
#include <hip/hip_runtime.h>
#include <math.h>

#define TT 8
#define NC 128
#define HH 128
#define WW 128
#define HWP (HH*WW)
#define IMG ((size_t)NC*HWP)

typedef __attribute__((ext_vector_type(8))) short bf16x8;
typedef __attribute__((ext_vector_type(4))) float f32x4;

__device__ __forceinline__ unsigned short f2bf_rn(float f) {
  unsigned u = __builtin_bit_cast(unsigned, f);
  unsigned r = u + 0x7FFFu + ((u >> 16) & 1u);
  return (unsigned short)(r >> 16);
}
__device__ __forceinline__ float bf2f(unsigned short h) {
  unsigned u = ((unsigned)h) << 16;
  return __builtin_bit_cast(float, u);
}

// ---------------- per-scale compile-time geometry ----------------
template<int S> struct SCg {
  static constexpr int PH   = 128 >> S;
  static constexpr int OH   = 1 << S;
  static constexpr int OHOW = OH*OH;
  static constexpr int N    = TT*OHOW;
  static constexpr int PHPW = PH*PH;
  static constexpr int D    = 32*PHPW;
  static constexpr int LPW  = 7 - S;
  static constexpr int LPP  = 14 - 2*S;
};

template<int S, int CS, int CB0>
__device__ __forceinline__ size_t win_addr(int b, int w, int f) {
  int t  = w >> (2*S);
  int rr = w & (SCg<S>::OHOW-1);
  int oy = rr >> S;
  int ox = rr & (SCg<S>::OH-1);
  int c  = f >> SCg<S>::LPP;
  int r2 = f & (SCg<S>::PHPW-1);
  int py = r2 >> SCg<S>::LPW;
  int px = r2 & (SCg<S>::PH-1);
  return ((size_t)((b*TT + t)*CS + CB0 + c))*HWP
       + (size_t)((oy*SCg<S>::PH + py)*WW) + ox*SCg<S>::PH + px;
}

// ---------------- 1a) Q projection (1x1 conv, all 128 channels) ----------
__global__ __launch_bounds__(256) void q_proj(
    const float* __restrict__ x,
    const float* __restrict__ wq, const float* __restrict__ bq,
    float* __restrict__ q)
{
  const int img = blockIdx.y;
  const int p0  = blockIdx.x * 128;
  __shared__ float wl[32][132];
  __shared__ float xl[32][132];
  const int tid = threadIdx.x;
  const int og = tid >> 4, pg = tid & 15;
  float acc[8][8];
  #pragma unroll
  for (int i=0;i<8;i++)
    #pragma unroll
    for (int j=0;j<8;j++) acc[i][j]=0.f;
  const float* xb = x + (size_t)img*IMG + p0;

  for (int k0=0; k0<128; k0+=32) {
    for (int idx=tid; idx<32*128; idx+=256) {
      int o = idx >> 5, cc = idx & 31;
      wl[cc][o] = wq[o*128 + k0 + cc];
    }
    for (int idx=tid; idx<32*128; idx+=256) {
      int cc = idx >> 7, p = idx & 127;
      xl[cc][p] = xb[(size_t)(k0+cc)*HWP + p];
    }
    __syncthreads();
    #pragma unroll
    for (int cc=0; cc<32; cc++) {
      float4 wf0 = *(const float4*)&wl[cc][og*8];
      float4 wf1 = *(const float4*)&wl[cc][og*8+4];
      float4 xf0 = *(const float4*)&xl[cc][pg*8];
      float4 xf1 = *(const float4*)&xl[cc][pg*8+4];
      float wv8[8] = {wf0.x,wf0.y,wf0.z,wf0.w,wf1.x,wf1.y,wf1.z,wf1.w};
      float xv8[8] = {xf0.x,xf0.y,xf0.z,xf0.w,xf1.x,xf1.y,xf1.z,xf1.w};
      #pragma unroll
      for (int i=0;i<8;i++)
        #pragma unroll
        for (int j=0;j<8;j++) acc[i][j] += wv8[i]*xv8[j];
    }
    __syncthreads();
  }
  #pragma unroll
  for (int i=0;i<8;i++) {
    int o = og*8 + i;
    float bs = bq[o];
    float* dst = q + ((size_t)img*NC + o)*HWP + p0 + pg*8;
    float4 r0 = {acc[i][0]+bs, acc[i][1]+bs, acc[i][2]+bs, acc[i][3]+bs};
    float4 r1 = {acc[i][4]+bs, acc[i][5]+bs, acc[i][6]+bs, acc[i][7]+bs};
    *(float4*)dst       = r0;
    *(float4*)(dst + 4) = r1;
  }
}

// ---------------- 1b) per-scale K,V slice projection ---------------------
template<int S>
__global__ __launch_bounds__(256) void kv_proj(
    const float* __restrict__ x,
    const float* __restrict__ wk, const float* __restrict__ bk,
    const float* __restrict__ wv, const float* __restrict__ bv,
    float* __restrict__ ko, float* __restrict__ vo)
{
  const int img = blockIdx.y;
  const int p0  = blockIdx.x * 128;
  __shared__ float wl[32][68];
  __shared__ float xl[32][132];
  const int tid = threadIdx.x;
  const int og = tid >> 4, pg = tid & 15;
  float acc[4][8];
  #pragma unroll
  for (int i=0;i<4;i++)
    #pragma unroll
    for (int j=0;j<8;j++) acc[i][j]=0.f;
  const float* xb = x + (size_t)img*IMG + p0;

  for (int k0=0; k0<128; k0+=32) {
    for (int idx=tid; idx<64*32; idx+=256) {
      int o = idx >> 5, cc = idx & 31;
      const float* wm = (o < 32) ? (wk + (size_t)(32*S + o)*128)
                                 : (wv + (size_t)(32*S + o - 32)*128);
      wl[cc][o] = wm[k0 + cc];
    }
    for (int idx=tid; idx<32*128; idx+=256) {
      int cc = idx >> 7, p = idx & 127;
      xl[cc][p] = xb[(size_t)(k0+cc)*HWP + p];
    }
    __syncthreads();
    #pragma unroll
    for (int cc=0; cc<32; cc++) {
      float4 wf = *(const float4*)&wl[cc][og*4];
      float4 xf0 = *(const float4*)&xl[cc][pg*8];
      float4 xf1 = *(const float4*)&xl[cc][pg*8+4];
      float wr[4] = {wf.x,wf.y,wf.z,wf.w};
      float xv8[8] = {xf0.x,xf0.y,xf0.z,xf0.w,xf1.x,xf1.y,xf1.z,xf1.w};
      #pragma unroll
      for (int i=0;i<4;i++)
        #pragma unroll
        for (int j=0;j<8;j++) acc[i][j] += wr[i]*xv8[j];
    }
    __syncthreads();
  }
  #pragma unroll
  for (int i=0;i<4;i++) {
    int o = og*4 + i;
    float bs; float* dst;
    if (o < 32) { bs = bk[32*S + o];      dst = ko + ((size_t)img*32 + o)*HWP      + p0 + pg*8; }
    else        { bs = bv[32*S + o - 32]; dst = vo + ((size_t)img*32 + o - 32)*HWP + p0 + pg*8; }
    float4 r0 = {acc[i][0]+bs, acc[i][1]+bs, acc[i][2]+bs, acc[i][3]+bs};
    float4 r1 = {acc[i][4]+bs, acc[i][5]+bs, acc[i][6]+bs, acc[i][7]+bs};
    *(float4*)dst       = r0;
    *(float4*)(dst + 4) = r1;
  }
}

// ---------------- 2a) scores, scale 0 ------------------------------------
__global__ __launch_bounds__(64) void scores_s0(
    const float* __restrict__ q, const float* __restrict__ kk,
    float* __restrict__ sc)
{
  constexpr int KC = 512;
  __shared__ float ql[8][KC+4], kl[8][KC+4];
  const int b  = blockIdx.y;
  const int k0 = blockIdx.x * KC;
  const int tid = threadIdx.x;
  for (int idx=tid; idx<8*KC; idx+=64) {
    int w = idx >> 9, c = idx & (KC-1);
    int f = k0 + c;
    int ch = f >> 14, r2 = f & 16383;
    ql[w][c] = q [((size_t)((b*TT + w)*NC + ch))*HWP + r2];
    kl[w][c] = kk[((size_t)((b*TT + w)*32 + ch))*HWP + r2];
  }
  __syncthreads();
  const int nn = tid >> 3, mm = tid & 7;
  float acc = 0.f;
  #pragma unroll 8
  for (int c=0; c<KC; c+=4) {
    float4 qf = *(const float4*)&ql[nn][c];
    float4 kf = *(const float4*)&kl[mm][c];
    acc += qf.x*kf.x + qf.y*kf.y + qf.z*kf.z + qf.w*kf.w;
  }
  atomicAdd(&sc[(b*8 + nn)*8 + mm], acc);
}

// ---------------- 2b) scores, scale 1 (fp32 gather-GEMM) ------------------
template<int S, int TILE>
__global__ __launch_bounds__(256) void scores_gemm(
    const float* __restrict__ q, const float* __restrict__ kmat,
    float* __restrict__ sc, int kchunk)
{
  constexpr int TS = TILE/16;
  constexpr int KC = 64;
  constexpr int NT = SCg<S>::N / TILE;
  __shared__ float ql[TILE][KC+2], kl[TILE][KC+2];
  const int b  = blockIdx.z;
  const int tn = blockIdx.y / NT, tm = blockIdx.y % NT;
  const int tid = threadIdx.x;
  const int rg = tid >> 4, cg = tid & 15;
  float acc[TS][TS];
  #pragma unroll
  for (int i=0;i<TS;i++)
    #pragma unroll
    for (int j=0;j<TS;j++) acc[i][j]=0.f;
  const int k0b = blockIdx.x * kchunk;

  for (int k0=k0b; k0<k0b+kchunk; k0+=KC) {
    for (int idx=tid; idx<TILE*KC; idx+=256) {
      int r = idx >> 6, c = idx & 63;
      ql[r][c] = q   [win_addr<S,128,32*S>(b, tn*TILE + r, k0 + c)];
      kl[r][c] = kmat[win_addr<S,32,0>   (b, tm*TILE + r, k0 + c)];
    }
    __syncthreads();
    #pragma unroll 8
    for (int c=0; c<KC; c+=2) {
      float2 qf[TS], kf[TS];
      #pragma unroll
      for (int i=0;i<TS;i++) qf[i] = *(const float2*)&ql[rg*TS+i][c];
      #pragma unroll
      for (int j=0;j<TS;j++) kf[j] = *(const float2*)&kl[cg*TS+j][c];
      #pragma unroll
      for (int i=0;i<TS;i++)
        #pragma unroll
        for (int j=0;j<TS;j++)
          acc[i][j] += qf[i].x*kf[j].x + qf[i].y*kf[j].y;
    }
    __syncthreads();
  }
  #pragma unroll
  for (int i=0;i<TS;i++)
    #pragma unroll
    for (int j=0;j<TS;j++)
      atomicAdd(&sc[((size_t)b*SCg<S>::N + tn*TILE + rg*TS + i)*SCg<S>::N
                    + tm*TILE + cg*TS + j], acc[i][j]);
}

// ---------------- 3) softmax over rows -----------------------------------
__global__ __launch_bounds__(256) void softmax_rows(
    float* __restrict__ s, int n, float rsd)
{
  __shared__ float red[256];
  float* p = s + (size_t)blockIdx.x * n;
  const int tid = threadIdx.x;
  float lm = -1e30f;
  for (int j=tid;j<n;j+=256) lm = fmaxf(lm, p[j]*rsd);
  red[tid]=lm; __syncthreads();
  for (int st=128; st>0; st>>=1) { if (tid<st) red[tid]=fmaxf(red[tid],red[tid+st]); __syncthreads(); }
  const float mx = red[0]; __syncthreads();
  float ls = 0.f;
  for (int j=tid;j<n;j+=256) { float e = expf(p[j]*rsd - mx); p[j]=e; ls+=e; }
  red[tid]=ls; __syncthreads();
  for (int st=128; st>0; st>>=1) { if (tid<st) red[tid]+=red[tid+st]; __syncthreads(); }
  const float inv = 1.f/red[0];
  for (int j=tid;j<n;j+=256) p[j]*=inv;
}

// ---------------- 4a) PV, scale 0 -----------------------------------------
__global__ __launch_bounds__(256) void pv_s0(
    const float* __restrict__ attn, const float* __restrict__ v,
    float* __restrict__ y)
{
  __shared__ float al[8][8];
  const int b = blockIdx.y;
  const int tid = threadIdx.x;
  if (tid < 64) al[tid>>3][tid&7] = attn[b*64 + tid];
  __syncthreads();
  const int f  = blockIdx.x*256 + tid;
  const int c  = f >> 14;
  const int r2 = f & 16383;
  float acc[8];
  #pragma unroll
  for (int i=0;i<8;i++) acc[i]=0.f;
  #pragma unroll
  for (int m=0;m<8;m++) {
    float vv = v[((size_t)((b*TT+m)*32 + c))*HWP + r2];
    #pragma unroll
    for (int nn=0;nn<8;nn++) acc[nn] += al[nn][m]*vv;
  }
  #pragma unroll
  for (int nn=0;nn<8;nn++)
    y[((size_t)((b*TT+nn)*NC + c))*HWP + r2] = acc[nn];
}

// ---------------- 4b) PV, scale 1 (fp32) ----------------------------------
template<int S>
__global__ __launch_bounds__(256) void pv_gemm(
    const float* __restrict__ attn, const float* __restrict__ v,
    float* __restrict__ y)
{
  constexpr int N_ = SCg<S>::N;
  constexpr int TN = (N_ < 128) ? N_ : 128;
  constexpr int WSB = TN/16;
  constexpr int KM = 32, TF = 64;
  __shared__ float al[KM][TN+4];
  __shared__ float vl[KM][TF+4];
  const int b  = blockIdx.z;
  const int w0 = blockIdx.y * TN;
  const int f0 = blockIdx.x * TF;
  const int tid = threadIdx.x;
  const int wg = tid >> 4, fg = tid & 15;
  float acc[WSB][4];
  #pragma unroll
  for (int i=0;i<WSB;i++)
    #pragma unroll
    for (int j=0;j<4;j++) acc[i][j]=0.f;

  for (int m0=0; m0<N_; m0+=KM) {
    for (int idx=tid; idx<KM*TN; idx+=256) {
      int mm = idx / TN, ww = idx % TN;
      al[mm][ww] = attn[((size_t)b*N_ + w0 + ww)*N_ + m0 + mm];
    }
    for (int idx=tid; idx<KM*TF; idx+=256) {
      int mm = idx >> 6, ff = idx & 63;
      vl[mm][ff] = v[win_addr<S,32,0>(b, m0 + mm, f0 + ff)];
    }
    __syncthreads();
    #pragma unroll
    for (int mm=0; mm<KM; mm++) {
      float4 vf = *(const float4*)&vl[mm][fg*4];
      #pragma unroll
      for (int i=0;i<WSB;i++) {
        float a = al[mm][wg*WSB + i];
        acc[i][0] += a*vf.x; acc[i][1] += a*vf.y;
        acc[i][2] += a*vf.z; acc[i][3] += a*vf.w;
      }
    }
    __syncthreads();
  }
  #pragma unroll
  for (int i=0;i<WSB;i++) {
    float4 r = {acc[i][0], acc[i][1], acc[i][2], acc[i][3]};
    *(float4*)&y[win_addr<S,128,32*S>(b, w0 + wg*WSB + i, f0 + fg*4)] = r;
  }
}

// ---------------- gather-pack q/k/v slice -> [b][n][d] bf16 hi/lo ----------
template<int S>
__global__ __launch_bounds__(256) void pack_qkv(
    const float* __restrict__ q, const float* __restrict__ kc, const float* __restrict__ vc,
    unsigned short* __restrict__ qh, unsigned short* __restrict__ qlo,
    unsigned short* __restrict__ kh, unsigned short* __restrict__ klo,
    unsigned short* __restrict__ vh, unsigned short* __restrict__ vlo)
{
  constexpr int D = SCg<S>::D;
  constexpr int LD = (S==2) ? 15 : 13;      // log2(D)
  const int which = blockIdx.y;
  size_t gi = ((size_t)blockIdx.x*256 + threadIdx.x) * 8;   // < 2*N*D = 2^23
  int b   = (int)(gi >> 22);                 // N*D = 2^22 for S=2,3
  int rem = (int)(gi & 4194303u);
  int n = rem >> LD;
  int d = rem & (D-1);
  const float* src; unsigned short *dh, *dl;
  size_t sa;
  if (which==0)      { sa = win_addr<S,128,32*S>(b,n,d); src=q;  dh=qh; dl=qlo; }
  else if (which==1) { sa = win_addr<S,32,0>(b,n,d);     src=kc; dh=kh; dl=klo; }
  else               { sa = win_addr<S,32,0>(b,n,d);     src=vc; dh=vh; dl=vlo; }
  float4 f0 = *(const float4*)(src + sa);
  float4 f1 = *(const float4*)(src + sa + 4);
  float ff[8] = {f0.x,f0.y,f0.z,f0.w,f1.x,f1.y,f1.z,f1.w};
  unsigned short hh[8], ll[8];
  #pragma unroll
  for (int j=0;j<8;++j) {
    hh[j] = f2bf_rn(ff[j]);
    ll[j] = f2bf_rn(ff[j] - bf2f(hh[j]));
  }
  *(uint4*)(dh + gi) = *(const uint4*)hh;
  *(uint4*)(dl + gi) = *(const uint4*)ll;
}

// ---------------- QK^T via MFMA (split-bf16), K-split + atomics -----------
template<int S, int KSPL>
__global__ __launch_bounds__(256) void scores_mfma(
    const unsigned short* __restrict__ qh, const unsigned short* __restrict__ qlo,
    const unsigned short* __restrict__ kh, const unsigned short* __restrict__ klo,
    float* __restrict__ sc)
{
  constexpr int N = SCg<S>::N, D = SCg<S>::D;
  constexpr int NT = N/64;
  constexpr int KCH = D / KSPL;
  __shared__ unsigned short qs[2][64*72], ks[2][64*72];
  const int b  = blockIdx.z;
  const int tn = blockIdx.y / NT, tm = blockIdx.y % NT;
  const int k0b = blockIdx.x * KCH;
  const int tid=threadIdx.x, lane=tid&63, wave=tid>>6;
  const int lrow=lane&15, lk=lane>>4;
  f32x4 acc[4];
  #pragma unroll
  for (int j=0;j<4;++j) acc[j] = (f32x4){0.f,0.f,0.f,0.f};
  const int r = tid>>2, seg = tid&3;
  const size_t qrow = ((size_t)b*N + tn*64 + r)*D;
  const size_t krow = ((size_t)b*N + tm*64 + r)*D;

  for (int k0=k0b; k0<k0b+KCH; k0+=64) {
    __syncthreads();
    *(uint4*)&qs[0][r*72+seg*16]   = *(const uint4*)(qh  + qrow + k0 + seg*16);
    *(uint4*)&qs[0][r*72+seg*16+8] = *(const uint4*)(qh  + qrow + k0 + seg*16+8);
    *(uint4*)&qs[1][r*72+seg*16]   = *(const uint4*)(qlo + qrow + k0 + seg*16);
    *(uint4*)&qs[1][r*72+seg*16+8] = *(const uint4*)(qlo + qrow + k0 + seg*16+8);
    *(uint4*)&ks[0][r*72+seg*16]   = *(const uint4*)(kh  + krow + k0 + seg*16);
    *(uint4*)&ks[0][r*72+seg*16+8] = *(const uint4*)(kh  + krow + k0 + seg*16+8);
    *(uint4*)&ks[1][r*72+seg*16]   = *(const uint4*)(klo + krow + k0 + seg*16);
    *(uint4*)&ks[1][r*72+seg*16+8] = *(const uint4*)(klo + krow + k0 + seg*16+8);
    __syncthreads();
    #pragma unroll
    for (int kk=0; kk<2; ++kk) {
      bf16x8 a_h = *(bf16x8*)&qs[0][(wave*16+lrow)*72 + kk*32 + lk*8];
      bf16x8 a_l = *(bf16x8*)&qs[1][(wave*16+lrow)*72 + kk*32 + lk*8];
      #pragma unroll
      for (int j=0;j<4;++j) {
        bf16x8 b_h = *(bf16x8*)&ks[0][(j*16+lrow)*72 + kk*32 + lk*8];
        bf16x8 b_l = *(bf16x8*)&ks[1][(j*16+lrow)*72 + kk*32 + lk*8];
        acc[j] = __builtin_amdgcn_mfma_f32_16x16x32_bf16(a_h, b_h, acc[j], 0,0,0);
        acc[j] = __builtin_amdgcn_mfma_f32_16x16x32_bf16(a_h, b_l, acc[j], 0,0,0);
        acc[j] = __builtin_amdgcn_mfma_f32_16x16x32_bf16(a_l, b_h, acc[j], 0,0,0);
      }
    }
  }
  #pragma unroll
  for (int j=0;j<4;++j) {
    int m = tm*64 + j*16 + lrow;
    #pragma unroll
    for (int i=0;i<4;++i) {
      int n = tn*64 + wave*16 + lk*4 + i;
      atomicAdd(&sc[((size_t)b*N + n)*N + m], acc[j][i]);
    }
  }
}

// ---------------- softmaxed attn -> bf16 hi/lo ----------------------------
__global__ __launch_bounds__(256) void attn_pack(
    const float* __restrict__ sc,
    unsigned short* __restrict__ ah, unsigned short* __restrict__ al)
{
  size_t i0 = ((size_t)blockIdx.x*256 + threadIdx.x) * 8;
  float4 f0 = *(const float4*)(sc + i0);
  float4 f1 = *(const float4*)(sc + i0 + 4);
  float ff[8] = {f0.x,f0.y,f0.z,f0.w,f1.x,f1.y,f1.z,f1.w};
  unsigned short hh[8], ll[8];
  #pragma unroll
  for (int j=0;j<8;++j) {
    hh[j] = f2bf_rn(ff[j]);
    ll[j] = f2bf_rn(ff[j] - bf2f(hh[j]));
  }
  *(uint4*)(ah + i0) = *(const uint4*)hh;
  *(uint4*)(al + i0) = *(const uint4*)ll;
}

// ---------------- PV via MFMA (A x V), V transposed in LDS ----------------
template<int S>
__global__ __launch_bounds__(256) void pv_mfma(
    const unsigned short* __restrict__ ah, const unsigned short* __restrict__ alo,
    const unsigned short* __restrict__ vh, const unsigned short* __restrict__ vlo,
    float* __restrict__ y)
{
  constexpr int N = SCg<S>::N, D = SCg<S>::D;
  __shared__ unsigned short as_[2][64*72], vs[2][64*72];
  const int d0 = blockIdx.x*64, n0 = blockIdx.y*64, b = blockIdx.z;
  const int tid=threadIdx.x, lane=tid&63, wave=tid>>6;
  const int lrow=lane&15, lk=lane>>4;
  f32x4 acc[4];
  #pragma unroll
  for (int j=0;j<4;++j) acc[j] = (f32x4){0.f,0.f,0.f,0.f};
  const int r = tid>>2, seg = tid&3;
  const int m8w = r>>3, m0w = r&7;      // for transpose write (ml = r)

  for (int m0=0; m0<N; m0+=64) {
    __syncthreads();
    // A staging: rows n, cols m (no transpose)
    size_t arow = ((size_t)b*N + n0 + r)*N + m0;
    *(uint4*)&as_[0][r*72+seg*16]   = *(const uint4*)(ah  + arow + seg*16);
    *(uint4*)&as_[0][r*72+seg*16+8] = *(const uint4*)(ah  + arow + seg*16+8);
    *(uint4*)&as_[1][r*72+seg*16]   = *(const uint4*)(alo + arow + seg*16);
    *(uint4*)&as_[1][r*72+seg*16+8] = *(const uint4*)(alo + arow + seg*16+8);
    // Vt staging: read V[m][d] coalesced, write transposed + XOR-swizzled
    size_t vrow = ((size_t)b*N + m0 + r)*D + d0;
    uint4 h0 = *(const uint4*)(vh  + vrow + seg*16);
    uint4 h1 = *(const uint4*)(vh  + vrow + seg*16+8);
    uint4 l0 = *(const uint4*)(vlo + vrow + seg*16);
    uint4 l1 = *(const uint4*)(vlo + vrow + seg*16+8);
    unsigned short hv[16], lv[16];
    *(uint4*)hv = h0; *(uint4*)(hv+8) = h1;
    *(uint4*)lv = l0; *(uint4*)(lv+8) = l1;
    #pragma unroll
    for (int jj=0;jj<16;++jj) {
      int dl = seg*16 + jj;
      int col = ((m8w ^ ((dl>>3)&7)) << 3) + m0w;
      vs[0][dl*72 + col] = hv[jj];
      vs[1][dl*72 + col] = lv[jj];
    }
    __syncthreads();
    #pragma unroll
    for (int kk=0; kk<2; ++kk) {
      int dl = wave*16 + lrow;
      int colr = (((kk*4+lk) ^ ((dl>>3)&7)) << 3);
      bf16x8 va_h = *(bf16x8*)&vs[0][dl*72 + colr];
      bf16x8 va_l = *(bf16x8*)&vs[1][dl*72 + colr];
      #pragma unroll
      for (int j=0;j<4;++j) {
        bf16x8 ab_h = *(bf16x8*)&as_[0][(j*16+lrow)*72 + kk*32 + lk*8];
        bf16x8 ab_l = *(bf16x8*)&as_[1][(j*16+lrow)*72 + kk*32 + lk*8];
        acc[j] = __builtin_amdgcn_mfma_f32_16x16x32_bf16(va_h, ab_h, acc[j], 0,0,0);
        acc[j] = __builtin_amdgcn_mfma_f32_16x16x32_bf16(va_h, ab_l, acc[j], 0,0,0);
        acc[j] = __builtin_amdgcn_mfma_f32_16x16x32_bf16(va_l, ab_h, acc[j], 0,0,0);
      }
    }
  }
  // epilogue: C row = d (lk*4+i), col = n (lrow); 4 consecutive d -> float4
  #pragma unroll
  for (int j=0;j<4;++j) {
    int n = n0 + j*16 + lrow;
    int d = d0 + wave*16 + lk*4;
    float4 w = {acc[j][0], acc[j][1], acc[j][2], acc[j][3]};
    *(float4*)&y[win_addr<S,128,32*S>(b, n, d)] = w;
  }
}

// ---------------- 5a) pack conv weights -> [tap][o][c] bf16 hi/lo ---------
__global__ __launch_bounds__(256) void pack_w(
    const float* __restrict__ wo,
    unsigned short* __restrict__ whi, unsigned short* __restrict__ wlo)
{
  int idx = blockIdx.x*256 + threadIdx.x;
  if (idx >= 9*128*128) return;
  int c = idx & 127, o = (idx >> 7) & 127, tap = idx >> 14;
  float f = wo[((size_t)o*128 + c)*9 + tap];
  unsigned short h = f2bf_rn(f);
  whi[idx] = h;
  wlo[idx] = f2bf_rn(f - bf2f(h));
}

// ---------------- 5b) pack attention output -> [img][row][px][c] hi/lo ----
__global__ __launch_bounds__(256) void pack_y(
    const float* __restrict__ y,
    unsigned short* __restrict__ yth, unsigned short* __restrict__ ytl)
{
  __shared__ float tl[32][130];
  const int row = blockIdx.x, img = blockIdx.y;
  const int tid = threadIdx.x;
  for (int c0=0; c0<128; c0+=32) {
    __syncthreads();
    #pragma unroll
    for (int e=0; e<16; ++e) {
      int idx = e*256 + tid;
      int cc = idx >> 7, px = idx & 127;
      tl[cc][px] = y[((size_t)img*NC + c0+cc)*HWP + row*WW + px];
    }
    __syncthreads();
    #pragma unroll
    for (int e=0; e<16; ++e) {
      int idx = e*256 + tid;
      int px = idx >> 5, cc = idx & 31;
      float f = tl[cc][px];
      unsigned short h = f2bf_rn(f);
      size_t oa = (((size_t)img*HH + row)*WW + px)*NC + c0 + cc;
      yth[oa] = h;
      ytl[oa] = f2bf_rn(f - bf2f(h));
    }
  }
}

// ---------------- 5c) 3x3 conv via MFMA (split-bf16, 3-term) --------------
__global__ __launch_bounds__(256) void conv3x3_mfma(
    const unsigned short* __restrict__ yth, const unsigned short* __restrict__ ytl,
    const unsigned short* __restrict__ whi, const unsigned short* __restrict__ wlo,
    const float* __restrict__ bo, float* __restrict__ out)
{
  constexpr int XP = 40;
  __shared__ unsigned short xh[130*XP], xlo[130*XP];
  __shared__ unsigned short wh[3*64*XP], wl2[3*64*XP];
  const int yrow = blockIdx.x, ob = blockIdx.y, img = blockIdx.z;
  const int o0 = ob*64;
  const int tid = threadIdx.x;
  const int lane = tid & 63, wave = tid >> 6;
  const int lrow = lane & 15, lk = lane >> 4;

  f32x4 acc[8];
  #pragma unroll
  for (int j=0;j<8;++j) acc[j] = (f32x4){0.f,0.f,0.f,0.f};

  if (tid < 80) {
    int off = (tid < 40) ? tid : 129*XP + (tid-40);
    xh[off] = 0; xlo[off] = 0;
  }

  for (int ky=0; ky<3; ++ky) {
    const int yy = yrow + ky - 1;
    if (yy < 0 || yy >= HH) continue;
    const unsigned short* ysh = yth + (((size_t)img*HH + yy)*WW)*NC;
    const unsigned short* ysl = ytl + (((size_t)img*HH + yy)*WW)*NC;
    for (int c0=0; c0<128; c0+=32) {
      __syncthreads();
      #pragma unroll
      for (int it=0; it<2; ++it) {
        int px = (tid >> 2) + it*64;
        int oc = tid & 3;
        const uint4 hv = *(const uint4*)(ysh + (size_t)px*NC + c0 + oc*8);
        const uint4 lv = *(const uint4*)(ysl + (size_t)px*NC + c0 + oc*8);
        *(uint4*)&xh [(px+1)*XP + oc*8] = hv;
        *(uint4*)&xlo[(px+1)*XP + oc*8] = lv;
      }
      #pragma unroll
      for (int it=0; it<3; ++it) {
        int idx = it*256 + tid;
        int kx = idx >> 8, rem = idx & 255;
        int o = rem >> 2, oc = rem & 3;
        size_t ga = ((size_t)((ky*3+kx)*128) + o0 + o)*128 + c0 + oc*8;
        *(uint4*)&wh [(kx*64+o)*XP + oc*8] = *(const uint4*)(whi + ga);
        *(uint4*)&wl2[(kx*64+o)*XP + oc*8] = *(const uint4*)(wlo + ga);
      }
      __syncthreads();
      #pragma unroll
      for (int kx=0; kx<3; ++kx) {
        bf16x8 ah = *(bf16x8*)&wh [(kx*64 + wave*16 + lrow)*XP + lk*8];
        bf16x8 al = *(bf16x8*)&wl2[(kx*64 + wave*16 + lrow)*XP + lk*8];
        #pragma unroll
        for (int j=0;j<8;++j) {
          int r = j*16 + lrow + kx;
          bf16x8 bh = *(bf16x8*)&xh [r*XP + lk*8];
          bf16x8 bl = *(bf16x8*)&xlo[r*XP + lk*8];
          acc[j] = __builtin_amdgcn_mfma_f32_16x16x32_bf16(ah, bh, acc[j], 0,0,0);
          acc[j] = __builtin_amdgcn_mfma_f32_16x16x32_bf16(ah, bl, acc[j], 0,0,0);
          acc[j] = __builtin_amdgcn_mfma_f32_16x16x32_bf16(al, bh, acc[j], 0,0,0);
        }
      }
    }
  }
  float bs[4];
  #pragma unroll
  for (int i=0;i<4;++i) bs[i] = bo[o0 + wave*16 + lk*4 + i];
  #pragma unroll
  for (int j=0;j<8;++j) {
    #pragma unroll
    for (int i=0;i<4;++i) {
      int o = o0 + wave*16 + lk*4 + i;
      float r = fmaxf(acc[j][i] + bs[i], 0.f);
      out[((size_t)img*NC + o)*HWP + yrow*WW + j*16 + lrow] = r;
    }
  }
}

// ---------------- launcher -------------------------------------------------
extern "C" void kernel_launch(void* const* d_in, const int* in_sizes, int n_in,
                              void* d_out, int out_size, void* d_ws, size_t ws_size,
                              hipStream_t stream) {
  const float* x  = (const float*)d_in[0];
  const float* wq = (const float*)d_in[1];
  const float* bq = (const float*)d_in[2];
  const float* wk = (const float*)d_in[3];
  const float* bk = (const float*)d_in[4];
  const float* wv = (const float*)d_in[5];
  const float* bv = (const float*)d_in[6];
  const float* wo = (const float*)d_in[7];
  const float* bo = (const float*)d_in[8];
  float* out = (float*)d_out;

  // ws layout (as before, ~338 MB) + 2.1 MB attn bf16.
  float* q    = (float*)d_ws;
  float* kbuf = q    + 33554432ull;
  float* vbuf = kbuf + 8388608ull;
  float* sc   = vbuf + 8388608ull;
  unsigned short* whi_ = (unsigned short*)(sc + 524288ull);
  unsigned short* wlo_ = whi_ + 147456ull;
  unsigned short* yth  = wlo_ + 147456ull;
  unsigned short* ytl  = yth  + 33554432ull;
  // qkv bf16 buffers alias yth/ytl region (dead until pack_y): 6 x 8,388,608 ush
  unsigned short* qh  = yth;
  unsigned short* ql_ = qh  + 8388608ull;
  unsigned short* kh  = ql_ + 8388608ull;
  unsigned short* kl  = kh  + 8388608ull;
  unsigned short* vh  = kl  + 8388608ull;
  unsigned short* vl  = vh  + 8388608ull;
  // attn bf16 (new, appended): 2 x 524,288 ush
  unsigned short* ah  = ytl + 33554432ull;
  unsigned short* al  = ah  + 524288ull;

  pack_w<<<576, 256, 0, stream>>>(wo, whi_, wlo_);
  q_proj<<<dim3(128,16), 256, 0, stream>>>(x, wq, bq, q);

  // ---- scale 0 (fp32 path) ----
  kv_proj<0><<<dim3(128,16), 256, 0, stream>>>(x, wk,bk, wv,bv, kbuf, vbuf);
  hipMemsetAsync(sc, 0, (size_t)2*8*8*sizeof(float), stream);
  scores_s0<<<dim3(1024,2), 64, 0, stream>>>(q, kbuf, sc);
  softmax_rows<<<2*8, 256, 0, stream>>>(sc, 8, 1.0f/sqrtf(524288.f));
  pv_s0<<<dim3(2048,2), 256, 0, stream>>>(sc, vbuf, q);

  // ---- scale 1 (fp32 path) ----
  kv_proj<1><<<dim3(128,16), 256, 0, stream>>>(x, wk,bk, wv,bv, kbuf, vbuf);
  hipMemsetAsync(sc, 0, (size_t)2*32*32*sizeof(float), stream);
  scores_gemm<1,32><<<dim3(256,1,2), 256, 0, stream>>>(q, kbuf, sc, 512);
  softmax_rows<<<2*32, 256, 0, stream>>>(sc, 32, 1.0f/sqrtf(131072.f));
  pv_gemm<1><<<dim3(131072/64, 1, 2), 256, 0, stream>>>(sc, vbuf, q);

  // ---- scale 2 (MFMA path) ----
  kv_proj<2><<<dim3(128,16), 256, 0, stream>>>(x, wk,bk, wv,bv, kbuf, vbuf);
  pack_qkv<2><<<dim3(4096,3), 256, 0, stream>>>(q, kbuf, vbuf, qh,ql_, kh,kl, vh,vl);
  hipMemsetAsync(sc, 0, (size_t)2*128*128*sizeof(float), stream);
  scores_mfma<2,64><<<dim3(64,4,2), 256, 0, stream>>>(qh,ql_, kh,kl, sc);
  softmax_rows<<<2*128, 256, 0, stream>>>(sc, 128, 1.0f/sqrtf(32768.f));
  attn_pack<<<16, 256, 0, stream>>>(sc, ah, al);
  pv_mfma<2><<<dim3(512,2,2), 256, 0, stream>>>(ah,al, vh,vl, q);

  // ---- scale 3 (MFMA path) ----
  kv_proj<3><<<dim3(128,16), 256, 0, stream>>>(x, wk,bk, wv,bv, kbuf, vbuf);
  pack_qkv<3><<<dim3(4096,3), 256, 0, stream>>>(q, kbuf, vbuf, qh,ql_, kh,kl, vh,vl);
  hipMemsetAsync(sc, 0, (size_t)2*512*512*sizeof(float), stream);
  scores_mfma<3,16><<<dim3(16,64,2), 256, 0, stream>>>(qh,ql_, kh,kl, sc);
  softmax_rows<<<2*512, 256, 0, stream>>>(sc, 512, 1.0f/sqrtf(8192.f));
  attn_pack<<<256, 256, 0, stream>>>(sc, ah, al);
  pv_mfma<3><<<dim3(128,8,2), 256, 0, stream>>>(ah,al, vh,vl, q);

  // ---- finale ----
  pack_y<<<dim3(128,16), 256, 0, stream>>>(q, yth, ytl);
  conv3x3_mfma<<<dim3(128, 2, 16), 256, 0, stream>>>(yth, ytl, whi_, wlo_, bo, out);
}